// Round 3
// baseline (710.332 us; speedup 1.0000x reference)
//
#include <hip/hip_runtime.h>

typedef __bf16 bf16;
typedef __bf16 bf16x8 __attribute__((ext_vector_type(8)));
typedef float f32x4 __attribute__((ext_vector_type(4)));

#define MFMA16(a,b,c) __builtin_amdgcn_mfma_f32_16x16x32_bf16(a,b,c,0,0,0)

#define N_Q   4096
#define DFEAT 512
#define KQ    8192
#define NLAB  128
#define NHEAD 8

// ---------------- workspace layout (bytes) ----------------
#define MBv (1024ull*1024ull)
#define OFF_COUNTS 0ull
#define OFF_MODE   512ull
#define OFF_FLAGS  1024ull
#define OFF_SEL    (64ull*1024ull)
#define OFF_FQ1    (1ull*MBv)   // 8192x512 bf16 = 8MB   (fq2 adjacent)
#define OFF_FQ2    (9ull*MBv)
#define OFF_LQ1    (17ull*MBv)  // 8192x128 bf16 = 2MB   (lq2 adjacent)
#define OFF_LQ2    (19ull*MBv)
#define OFF_Q1     (21ull*MBv)  // 4096x512 bf16 = 4MB
#define OFF_Q2     (25ull*MBv)
#define OFF_K1     (29ull*MBv)  // 16384x512 bf16 = 16MB (both streams)
#define OFF_WQT    (45ull*MBv)
#define OFF_WKT    (46ull*MBv)
#define OFF_WOT    (47ull*MBv)
#define OFF_VWT    (48ull*MBv)  // 128x16384 bf16 = 4MB (VW^T, kv-swizzled, both streams)
#define OFF_ACC    (52ull*MBv)  // 2x4096x128 f32 = 4MB

// ---------------- dtype-agnostic loads ----------------
__device__ __forceinline__ float loads(const void* p, size_t i, int f32m) {
    return f32m ? ((const float*)p)[i] : (float)((const bf16*)p)[i];
}
__device__ __forceinline__ bf16x8 load8(const void* p, size_t i, int f32m) {
    bf16x8 r;
    if (f32m) {
        const float4* q = (const float4*)((const float*)p + i);
        float4 f0 = q[0], f1 = q[1];
        r[0] = (bf16)f0.x; r[1] = (bf16)f0.y; r[2] = (bf16)f0.z; r[3] = (bf16)f0.w;
        r[4] = (bf16)f1.x; r[5] = (bf16)f1.y; r[6] = (bf16)f1.z; r[7] = (bf16)f1.w;
    } else {
        r = *(const bf16x8*)((const bf16*)p + i);
    }
    return r;
}

// ---------------- dtype detector ----------------
__global__ void detect_kernel(const void* probe, int* mode) {
    const unsigned short* u = (const unsigned short*)probe;
    int t = threadIdx.x;
    int bad = 0;
    for (int i = t; i < 2048; i += 256) {
        unsigned short v = u[2 * i];
        int e = (v >> 7) & 0xFF;
        if (e > 140 || (e < 60 && e != 0)) bad++;
    }
    __shared__ int sb[256];
    sb[t] = bad;
    __syncthreads();
    for (int off = 128; off; off >>= 1) {
        if (t < off) sb[t] += sb[t + off];
        __syncthreads();
    }
    if (t == 0) mode[0] = (sb[0] > 200) ? 1 : 0;
}

// ---------------- flag: row-max > 0.95 ----------------
__global__ void flag_kernel(const void* __restrict__ ulb1, const void* __restrict__ ulb2,
                            int* __restrict__ flags, const int* __restrict__ modep) {
    int f32m = *modep;
    int row = blockIdx.x, s = blockIdx.y, t = threadIdx.x; // 64 threads
    const void* p = s ? ulb2 : ulb1;
    size_t base = (size_t)row * NLAB;
    float m = fmaxf(loads(p, base + t, f32m), loads(p, base + t + 64, f32m));
    #pragma unroll
    for (int off = 32; off; off >>= 1) m = fmaxf(m, __shfl_xor(m, off));
    if (t == 0) flags[s * N_Q + row] = (m > 0.95f) ? 1 : 0;
}

// ---------------- scan: stable compaction ----------------
__global__ void scan_kernel(const int* __restrict__ flags, int* __restrict__ sel,
                            int* __restrict__ counts) {
    int s = blockIdx.x, t = threadIdx.x; // 1024 threads
    const int* f = flags + s * N_Q;
    int* selp = sel + s * N_Q;
    __shared__ int ls[1024];
    int f0 = f[t*4], f1 = f[t*4+1], f2 = f[t*4+2], f3 = f[t*4+3];
    int local = f0 + f1 + f2 + f3;
    ls[t] = local;
    __syncthreads();
    for (int off = 1; off < 1024; off <<= 1) {
        int v = (t >= off) ? ls[t - off] : 0;
        __syncthreads();
        ls[t] += v;
        __syncthreads();
    }
    int pos = ls[t] - local;
    if (f0) selp[pos++] = t*4;
    if (f1) selp[pos++] = t*4+1;
    if (f2) selp[pos++] = t*4+2;
    if (f3) selp[pos++] = t*4+3;
    if (t == 1023) counts[s] = ls[1023];
}

// ---------------- build queues ----------------
__global__ void buildq_kernel(const void* __restrict__ anchor, const void* __restrict__ positive,
                              const void* __restrict__ lbfeat, const void* __restrict__ lboh,
                              const void* __restrict__ ulb1, const void* __restrict__ ulb2,
                              const void* __restrict__ fq1i, const void* __restrict__ fq2i,
                              const void* __restrict__ lq1i, const void* __restrict__ lq2i,
                              const int* __restrict__ sel, const int* __restrict__ counts,
                              bf16* __restrict__ fq1o, bf16* __restrict__ fq2o,
                              bf16* __restrict__ lq1o, bf16* __restrict__ lq2o,
                              const int* __restrict__ modep) {
    int f32m = *modep;
    int i = blockIdx.x, s = blockIdx.y, t = threadIdx.x; // 128 threads
    int C = counts[s];
    const void *fb, *lb;
    size_t frow, lrow;
    if (i < C) {
        int r = sel[s * N_Q + i];
        fb = s ? positive : anchor; frow = r;
        lb = s ? ulb2 : ulb1;       lrow = r;
    } else if (i < C + 512) {
        int r = i - C + s * 512;
        fb = lbfeat; frow = r;
        lb = lboh;   lrow = r;
    } else {
        int r = i - C - 512;
        fb = s ? fq2i : fq1i; frow = r;
        lb = s ? lq2i : lq1i; lrow = r;
    }
    bf16* fd = (s ? fq2o : fq1o) + (size_t)i * DFEAT;
    bf16* ld = (s ? lq2o : lq1o) + (size_t)i * NLAB;
    if (t < 64)      *(bf16x8*)&fd[t * 8]        = load8(fb, frow * DFEAT + (size_t)t * 8, f32m);
    else if (t < 80) *(bf16x8*)&ld[(t - 64) * 8] = load8(lb, lrow * NLAB + (size_t)(t - 64) * 8, f32m);
}

// ---------------- square transpose (weights) -> bf16 ----------------
__global__ void transpose_kernel(const void* __restrict__ W, bf16* __restrict__ T, int n,
                                 const int* __restrict__ modep) {
    int f32m = *modep;
    __shared__ bf16 tile[32][33];
    int bx = blockIdx.x * 32, by = blockIdx.y * 32;
    int tx = threadIdx.x & 31, ty = threadIdx.x >> 5;
    for (int r = ty; r < 32; r += 8) tile[r][tx] = (bf16)loads(W, (size_t)(by + r) * n + bx + tx, f32m);
    __syncthreads();
    for (int r = ty; r < 32; r += 8) T[(size_t)(bx + r) * n + by + tx] = tile[tx][r];
}

// ---------------- NT GEMM: C = alpha * A @ Bt^T; optional kv-swizzle on col ----------------
__launch_bounds__(256, 2)
__global__ void gemm_nt(const void* __restrict__ A, const bf16* __restrict__ B,
                        bf16* __restrict__ C, int M, int N, int Kd, float alpha,
                        const int* __restrict__ modep, int a_raw, int swz) {
    int f32m = a_raw ? *modep : 0;
    __shared__ __align__(16) bf16 As[128 * 72];
    __shared__ __align__(16) bf16 Bs[128 * 72];
    int m0 = blockIdx.x * 128, n0 = blockIdx.y * 128;
    int t = threadIdx.x, lane = t & 63, wid = t >> 6;
    int quad = lane >> 4, l15 = lane & 15;
    int wrow = (wid >> 1) * 64, wcol = (wid & 1) * 64;
    int srow = t >> 1, sseg = t & 1;
    f32x4 acc[4][4] = {};
    for (int k0 = 0; k0 < Kd; k0 += 32) {
        __syncthreads();
        bf16x8 a0 = load8(A, (size_t)(m0 + srow) * Kd + k0 + sseg * 8, f32m);
        bf16x8 a1 = load8(A, (size_t)(m0 + srow) * Kd + k0 + (sseg + 2) * 8, f32m);
        const uint4* gb = (const uint4*)(B + (size_t)(n0 + srow) * Kd + k0);
        uint4 b0 = gb[sseg], b1 = gb[sseg + 2];
        *(bf16x8*)&As[srow * 72 + sseg * 8]       = a0;
        *(bf16x8*)&As[srow * 72 + (sseg + 2) * 8] = a1;
        *(uint4*)&Bs[srow * 72 + sseg * 8]        = b0;
        *(uint4*)&Bs[srow * 72 + (sseg + 2) * 8]  = b1;
        __syncthreads();
        bf16x8 af[4], bfr[4];
        #pragma unroll
        for (int mt = 0; mt < 4; mt++) af[mt]  = *(const bf16x8*)&As[(wrow + mt*16 + l15) * 72 + quad * 8];
        #pragma unroll
        for (int nt = 0; nt < 4; nt++) bfr[nt] = *(const bf16x8*)&Bs[(wcol + nt*16 + l15) * 72 + quad * 8];
        #pragma unroll
        for (int mt = 0; mt < 4; mt++)
            #pragma unroll
            for (int nt = 0; nt < 4; nt++)
                acc[mt][nt] = MFMA16(af[mt], bfr[nt], acc[mt][nt]);
    }
    #pragma unroll
    for (int mt = 0; mt < 4; mt++)
        #pragma unroll
        for (int nt = 0; nt < 4; nt++)
            #pragma unroll
            for (int r = 0; r < 4; r++) {
                int row = m0 + wrow + mt*16 + quad*4 + r;
                int col = n0 + wcol + nt*16 + l15;
                if (swz) col = (col & ~31) | (((col & 12) << 1) | ((col & 16) >> 2) | (col & 3));
                C[(size_t)row * N + col] = (bf16)(acc[mt][nt][r] * alpha);
            }
}

// ---------------- flash v2: S^T scheme, P stays in registers, V from global ----------------
__launch_bounds__(256, 2)
__global__ void flash2_kernel(const bf16* __restrict__ q1, const bf16* __restrict__ q2,
                              const bf16* __restrict__ kbase, const bf16* __restrict__ vbase,
                              float* __restrict__ acc_out) {
    __shared__ __align__(16) bf16 Kt[64 * 72];
    int qb = blockIdx.x, h = blockIdx.y, s = blockIdx.z;
    const bf16* Q  = s ? q2 : q1;
    const bf16* Kp = kbase + (size_t)s * KQ * DFEAT + h * 64;
    const bf16* Vp = vbase + (size_t)s * KQ;          // row pitch 2*KQ, stream offset in cols
    int t = threadIdx.x, lane = t & 63, wid = t >> 6;
    int quad = lane >> 4, l15 = lane & 15;
    int qbase = qb * 128 + wid * 32;

    // Q B-frags (registers for whole kernel)
    bf16x8 qf[2][2];
    #pragma unroll
    for (int mt = 0; mt < 2; mt++)
        #pragma unroll
        for (int ch = 0; ch < 2; ch++)
            qf[mt][ch] = *(const bf16x8*)(Q + (size_t)(qbase + mt*16 + l15) * DFEAT + h*64 + ch*32 + quad*8);

    // K staging: 4 lanes/row, granule-interleaved (conflict-free phases)
    int kr = t >> 2, ks = t & 3;
    const bf16* kg = Kp + (size_t)kr * DFEAT + ks * 16;
    bf16* kw = &Kt[kr * 72 + ks * 16];

    uint4 ka = *(const uint4*)kg, kb2 = *(const uint4*)(kg + 8);
    *(uint4*)kw = ka; *(uint4*)(kw + 8) = kb2;
    __syncthreads();

    f32x4 O[2][8] = {};
    float lrun[2] = {0.f, 0.f};

    for (int kv0 = 0; kv0 < KQ; kv0 += 64) {
        // prefetch next K chunk into registers (hidden under compute)
        if (kv0 + 64 < KQ) {
            const bf16* kn = kg + (size_t)(kv0 + 64) * DFEAT;
            ka = *(const uint4*)kn; kb2 = *(const uint4*)(kn + 8);
        }
        // V fragments direct from global (kv-swizzled layout -> plain b128)
        bf16x8 vbr[8][2];
        #pragma unroll
        for (int ct = 0; ct < 8; ct++)
            #pragma unroll
            for (int g = 0; g < 2; g++)
                vbr[ct][g] = *(const bf16x8*)(Vp + (size_t)(ct*16 + l15) * (2*KQ) + kv0 + g*32 + quad*8);

        // S^T = K · Q^T : D[m=kv][n=q]
        f32x4 S[2][4];
        #pragma unroll
        for (int nt = 0; nt < 4; nt++) {
            bf16x8 kf0 = *(const bf16x8*)&Kt[(nt*16 + l15) * 72 + quad * 8];
            bf16x8 kf1 = *(const bf16x8*)&Kt[(nt*16 + l15) * 72 + 32 + quad * 8];
            #pragma unroll
            for (int mt = 0; mt < 2; mt++) {
                f32x4 a = {};
                a = MFMA16(kf0, qf[mt][0], a);
                a = MFMA16(kf1, qf[mt][1], a);
                S[mt][nt] = a;
            }
        }
        // exp2 + pack directly into PV A-fragments (identity lane mapping)
        bf16x8 P[2][2];
        #pragma unroll
        for (int mt = 0; mt < 2; mt++) {
            float lsum = 0.f;
            #pragma unroll
            for (int g = 0; g < 2; g++) {
                bf16x8 p;
                #pragma unroll
                for (int r = 0; r < 4; r++) {
                    float e0 = exp2f(S[mt][2*g][r]);
                    float e1 = exp2f(S[mt][2*g+1][r]);
                    p[r]     = (bf16)e0;
                    p[4 + r] = (bf16)e1;
                    lsum += e0 + e1;
                }
                P[mt][g] = p;
            }
            lrun[mt] += lsum;
        }
        // O[q][c] += P · VW
        #pragma unroll
        for (int ct = 0; ct < 8; ct++)
            #pragma unroll
            for (int mt = 0; mt < 2; mt++) {
                O[mt][ct] = MFMA16(P[mt][0], vbr[ct][0], O[mt][ct]);
                O[mt][ct] = MFMA16(P[mt][1], vbr[ct][1], O[mt][ct]);
            }
        if (kv0 + 64 < KQ) {
            __syncthreads();
            *(uint4*)kw = ka; *(uint4*)(kw + 8) = kb2;
            __syncthreads();
        }
    }
    // final l reduction across quads (lanes sharing l15)
    #pragma unroll
    for (int mt = 0; mt < 2; mt++) {
        lrun[mt] += __shfl_xor(lrun[mt], 16);
        lrun[mt] += __shfl_xor(lrun[mt], 32);
    }
    #pragma unroll
    for (int mt = 0; mt < 2; mt++)
        #pragma unroll
        for (int r = 0; r < 4; r++) {
            float lr = __shfl(lrun[mt], quad * 4 + r);
            float inv = 1.0f / (8.0f * lr);
            int row = qbase + mt*16 + quad*4 + r;
            #pragma unroll
            for (int ct = 0; ct < 8; ct++)
                atomicAdd(&acc_out[((size_t)s * N_Q + row) * NLAB + ct*16 + l15], O[mt][ct][r] * inv);
        }
}

// ---------------- bias + cast ----------------
__global__ void bias_kernel(const float* __restrict__ acc, const void* __restrict__ bo,
                            void* __restrict__ out, const int* __restrict__ modep) {
    int f32m = *modep;
    int idx = blockIdx.x * 256 + threadIdx.x;
    float v = acc[idx] + loads(bo, idx & (NLAB - 1), f32m);
    if (f32m) ((float*)out)[idx] = v;
    else      ((bf16*)out)[idx] = (bf16)v;
}

extern "C" void kernel_launch(void* const* d_in, const int* in_sizes, int n_in,
                              void* d_out, int out_size, void* d_ws, size_t ws_size,
                              hipStream_t stream) {
    const void* anchor   = d_in[0];
    const void* positive = d_in[1];
    const void* lbfeat   = d_in[2];
    const void* lboh     = d_in[3];
    const void* ulb1     = d_in[5];
    const void* ulb2     = d_in[6];
    const void* fq1i     = d_in[7];
    const void* fq2i     = d_in[8];
    const void* lq1i     = d_in[9];
    const void* lq2i     = d_in[10];
    const void* Wq       = d_in[11];
    const void* Wk       = d_in[12];
    const void* Wo       = d_in[13];
    const void* bo       = d_in[14];

    char* ws = (char*)d_ws;
    int*  counts = (int*)(ws + OFF_COUNTS);
    int*  modep  = (int*)(ws + OFF_MODE);
    int*  flags  = (int*)(ws + OFF_FLAGS);
    int*  sel    = (int*)(ws + OFF_SEL);
    bf16* fq1  = (bf16*)(ws + OFF_FQ1);
    bf16* fq2  = (bf16*)(ws + OFF_FQ2);
    bf16* lq1  = (bf16*)(ws + OFF_LQ1);
    bf16* lq2  = (bf16*)(ws + OFF_LQ2);
    bf16* q1   = (bf16*)(ws + OFF_Q1);
    bf16* q2   = (bf16*)(ws + OFF_Q2);
    bf16* k1   = (bf16*)(ws + OFF_K1);
    bf16* wqT  = (bf16*)(ws + OFF_WQT);
    bf16* wkT  = (bf16*)(ws + OFF_WKT);
    bf16* woT  = (bf16*)(ws + OFF_WOT);
    bf16* vwt  = (bf16*)(ws + OFF_VWT);
    float* accb = (float*)(ws + OFF_ACC);

    hipMemsetAsync(accb, 0, (size_t)2 * N_Q * NLAB * sizeof(float), stream);

    detect_kernel<<<1, 256, 0, stream>>>(anchor, modep);
    flag_kernel<<<dim3(N_Q, 2), 64, 0, stream>>>(ulb1, ulb2, flags, modep);
    scan_kernel<<<2, 1024, 0, stream>>>(flags, sel, counts);
    buildq_kernel<<<dim3(KQ, 2), 128, 0, stream>>>(anchor, positive, lbfeat, lboh, ulb1, ulb2,
                                                   fq1i, fq2i, lq1i, lq2i, sel, counts,
                                                   fq1, fq2, lq1, lq2, modep);
    transpose_kernel<<<dim3(16, 16), 256, 0, stream>>>(Wq, wqT, 512, modep);
    transpose_kernel<<<dim3(16, 16), 256, 0, stream>>>(Wk, wkT, 512, modep);
    transpose_kernel<<<dim3(4, 4), 256, 0, stream>>>(Wo, woT, 128, modep);

    // q = (x @ Wq) * dh^-0.5 * log2(e)   (exp2-folded scale)
    const float qalpha = 0.125f * 1.44269504088896f;
    gemm_nt<<<dim3(32, 4), 256, 0, stream>>>(anchor,   wqT, q1, 4096, 512, 512, qalpha, modep, 1, 0);
    gemm_nt<<<dim3(32, 4), 256, 0, stream>>>(positive, wqT, q2, 4096, 512, 512, qalpha, modep, 1, 0);
    // k = [fq1;fq2] @ Wk  (merged, M=16384)
    gemm_nt<<<dim3(128, 4), 256, 0, stream>>>(fq1, wkT, k1, 16384, 512, 512, 1.0f, modep, 0, 0);
    // VW^T[c][kv] = Wo^T @ lq^T, merged N=16384, kv-swizzled columns for direct B-frag loads
    gemm_nt<<<dim3(1, 128), 256, 0, stream>>>(woT, lq1, vwt, 128, 16384, 128, 1.0f, modep, 0, 1);

    flash2_kernel<<<dim3(32, NHEAD, 2), 256, 0, stream>>>(q1, q2, k1, vwt, accb);
    bias_kernel<<<(2 * N_Q * NLAB) / 256, 256, 0, stream>>>(accb, bo, d_out, modep);
}

// Round 4
// 456.989 us; speedup vs baseline: 1.5544x; 1.5544x over previous
//
#include <hip/hip_runtime.h>

typedef __bf16 bf16;
typedef __bf16 bf16x8 __attribute__((ext_vector_type(8)));
typedef float f32x4 __attribute__((ext_vector_type(4)));

#define MFMA16(a,b,c) __builtin_amdgcn_mfma_f32_16x16x32_bf16(a,b,c,0,0,0)

#define N_Q   4096
#define DFEAT 512
#define KQ    8192
#define NLAB  128
#define NHEAD 8

// ---------------- workspace layout (bytes) ----------------
#define MBv (1024ull*1024ull)
#define OFF_COUNTS 0ull
#define OFF_MODE   512ull
#define OFF_FLAGS  1024ull
#define OFF_SEL    (64ull*1024ull)
#define OFF_FQ1    (1ull*MBv)   // 8192x512 bf16 = 8MB   (fq2 adjacent)
#define OFF_FQ2    (9ull*MBv)
#define OFF_LQ1    (17ull*MBv)  // 8192x128 bf16 = 2MB   (lq2 adjacent)
#define OFF_LQ2    (19ull*MBv)
#define OFF_Q1     (21ull*MBv)  // 4096x512 bf16 = 4MB
#define OFF_Q2     (25ull*MBv)
#define OFF_K1     (29ull*MBv)  // 16384x512 bf16 = 16MB (both streams)
#define OFF_WQT    (45ull*MBv)
#define OFF_WKT    (46ull*MBv)
#define OFF_WOT    (47ull*MBv)
#define OFF_VWT    (48ull*MBv)  // 128x16384 bf16 = 4MB (VW^T, kv-swizzled, both streams)
#define OFF_ACC    (52ull*MBv)  // 2x4096x128 f32 = 4MB

// ---------------- dtype-agnostic loads ----------------
__device__ __forceinline__ float loads(const void* p, size_t i, int f32m) {
    return f32m ? ((const float*)p)[i] : (float)((const bf16*)p)[i];
}
__device__ __forceinline__ bf16x8 load8(const void* p, size_t i, int f32m) {
    bf16x8 r;
    if (f32m) {
        const float4* q = (const float4*)((const float*)p + i);
        float4 f0 = q[0], f1 = q[1];
        r[0] = (bf16)f0.x; r[1] = (bf16)f0.y; r[2] = (bf16)f0.z; r[3] = (bf16)f0.w;
        r[4] = (bf16)f1.x; r[5] = (bf16)f1.y; r[6] = (bf16)f1.z; r[7] = (bf16)f1.w;
    } else {
        r = *(const bf16x8*)((const bf16*)p + i);
    }
    return r;
}

// ---------------- dtype detector ----------------
__global__ void detect_kernel(const void* probe, int* mode) {
    const unsigned short* u = (const unsigned short*)probe;
    int t = threadIdx.x;
    int bad = 0;
    for (int i = t; i < 2048; i += 256) {
        unsigned short v = u[2 * i];
        int e = (v >> 7) & 0xFF;
        if (e > 140 || (e < 60 && e != 0)) bad++;
    }
    __shared__ int sb[256];
    sb[t] = bad;
    __syncthreads();
    for (int off = 128; off; off >>= 1) {
        if (t < off) sb[t] += sb[t + off];
        __syncthreads();
    }
    if (t == 0) mode[0] = (sb[0] > 200) ? 1 : 0;
}

// ---------------- flag: row-max > 0.95 ----------------
__global__ void flag_kernel(const void* __restrict__ ulb1, const void* __restrict__ ulb2,
                            int* __restrict__ flags, const int* __restrict__ modep) {
    int f32m = *modep;
    int row = blockIdx.x, s = blockIdx.y, t = threadIdx.x; // 64 threads
    const void* p = s ? ulb2 : ulb1;
    size_t base = (size_t)row * NLAB;
    float m = fmaxf(loads(p, base + t, f32m), loads(p, base + t + 64, f32m));
    #pragma unroll
    for (int off = 32; off; off >>= 1) m = fmaxf(m, __shfl_xor(m, off));
    if (t == 0) flags[s * N_Q + row] = (m > 0.95f) ? 1 : 0;
}

// ---------------- scan: stable compaction ----------------
__global__ void scan_kernel(const int* __restrict__ flags, int* __restrict__ sel,
                            int* __restrict__ counts) {
    int s = blockIdx.x, t = threadIdx.x; // 1024 threads
    const int* f = flags + s * N_Q;
    int* selp = sel + s * N_Q;
    __shared__ int ls[1024];
    int f0 = f[t*4], f1 = f[t*4+1], f2 = f[t*4+2], f3 = f[t*4+3];
    int local = f0 + f1 + f2 + f3;
    ls[t] = local;
    __syncthreads();
    for (int off = 1; off < 1024; off <<= 1) {
        int v = (t >= off) ? ls[t - off] : 0;
        __syncthreads();
        ls[t] += v;
        __syncthreads();
    }
    int pos = ls[t] - local;
    if (f0) selp[pos++] = t*4;
    if (f1) selp[pos++] = t*4+1;
    if (f2) selp[pos++] = t*4+2;
    if (f3) selp[pos++] = t*4+3;
    if (t == 1023) counts[s] = ls[1023];
}

// ---------------- build queues ----------------
__global__ void buildq_kernel(const void* __restrict__ anchor, const void* __restrict__ positive,
                              const void* __restrict__ lbfeat, const void* __restrict__ lboh,
                              const void* __restrict__ ulb1, const void* __restrict__ ulb2,
                              const void* __restrict__ fq1i, const void* __restrict__ fq2i,
                              const void* __restrict__ lq1i, const void* __restrict__ lq2i,
                              const int* __restrict__ sel, const int* __restrict__ counts,
                              bf16* __restrict__ fq1o, bf16* __restrict__ fq2o,
                              bf16* __restrict__ lq1o, bf16* __restrict__ lq2o,
                              const int* __restrict__ modep) {
    int f32m = *modep;
    int i = blockIdx.x, s = blockIdx.y, t = threadIdx.x; // 128 threads
    int C = counts[s];
    const void *fb, *lb;
    size_t frow, lrow;
    if (i < C) {
        int r = sel[s * N_Q + i];
        fb = s ? positive : anchor; frow = r;
        lb = s ? ulb2 : ulb1;       lrow = r;
    } else if (i < C + 512) {
        int r = i - C + s * 512;
        fb = lbfeat; frow = r;
        lb = lboh;   lrow = r;
    } else {
        int r = i - C - 512;
        fb = s ? fq2i : fq1i; frow = r;
        lb = s ? lq2i : lq1i; lrow = r;
    }
    bf16* fd = (s ? fq2o : fq1o) + (size_t)i * DFEAT;
    bf16* ld = (s ? lq2o : lq1o) + (size_t)i * NLAB;
    if (t < 64)      *(bf16x8*)&fd[t * 8]        = load8(fb, frow * DFEAT + (size_t)t * 8, f32m);
    else if (t < 80) *(bf16x8*)&ld[(t - 64) * 8] = load8(lb, lrow * NLAB + (size_t)(t - 64) * 8, f32m);
}

// ---------------- square transpose (weights) -> bf16 ----------------
__global__ void transpose_kernel(const void* __restrict__ W, bf16* __restrict__ T, int n,
                                 const int* __restrict__ modep) {
    int f32m = *modep;
    __shared__ bf16 tile[32][33];
    int bx = blockIdx.x * 32, by = blockIdx.y * 32;
    int tx = threadIdx.x & 31, ty = threadIdx.x >> 5;
    for (int r = ty; r < 32; r += 8) tile[r][tx] = (bf16)loads(W, (size_t)(by + r) * n + bx + tx, f32m);
    __syncthreads();
    for (int r = ty; r < 32; r += 8) T[(size_t)(bx + r) * n + by + tx] = tile[tx][r];
}

// ---------------- NT GEMM: C = alpha * A @ Bt^T; optional kv-swizzle; optional batch-2 ----------------
__launch_bounds__(256, 2)
__global__ void gemm_nt(const void* __restrict__ A, const void* __restrict__ A2,
                        const bf16* __restrict__ B,
                        bf16* __restrict__ C, bf16* __restrict__ C2,
                        int M, int N, int Kd, float alpha,
                        const int* __restrict__ modep, int a_raw, int swz) {
    int f32m = a_raw ? *modep : 0;
    if (blockIdx.z) { A = A2; C = C2; }
    __shared__ __align__(16) bf16 As[128 * 72];
    __shared__ __align__(16) bf16 Bs[128 * 72];
    int m0 = blockIdx.x * 128, n0 = blockIdx.y * 128;
    int t = threadIdx.x, lane = t & 63, wid = t >> 6;
    int quad = lane >> 4, l15 = lane & 15;
    int wrow = (wid >> 1) * 64, wcol = (wid & 1) * 64;
    int srow = t >> 1, sseg = t & 1;
    f32x4 acc[4][4] = {};
    for (int k0 = 0; k0 < Kd; k0 += 32) {
        __syncthreads();
        bf16x8 a0 = load8(A, (size_t)(m0 + srow) * Kd + k0 + sseg * 8, f32m);
        bf16x8 a1 = load8(A, (size_t)(m0 + srow) * Kd + k0 + (sseg + 2) * 8, f32m);
        const uint4* gb = (const uint4*)(B + (size_t)(n0 + srow) * Kd + k0);
        uint4 b0 = gb[sseg], b1 = gb[sseg + 2];
        *(bf16x8*)&As[srow * 72 + sseg * 8]       = a0;
        *(bf16x8*)&As[srow * 72 + (sseg + 2) * 8] = a1;
        *(uint4*)&Bs[srow * 72 + sseg * 8]        = b0;
        *(uint4*)&Bs[srow * 72 + (sseg + 2) * 8]  = b1;
        __syncthreads();
        bf16x8 af[4], bfr[4];
        #pragma unroll
        for (int mt = 0; mt < 4; mt++) af[mt]  = *(const bf16x8*)&As[(wrow + mt*16 + l15) * 72 + quad * 8];
        #pragma unroll
        for (int nt = 0; nt < 4; nt++) bfr[nt] = *(const bf16x8*)&Bs[(wcol + nt*16 + l15) * 72 + quad * 8];
        #pragma unroll
        for (int mt = 0; mt < 4; mt++)
            #pragma unroll
            for (int nt = 0; nt < 4; nt++)
                acc[mt][nt] = MFMA16(af[mt], bfr[nt], acc[mt][nt]);
    }
    #pragma unroll
    for (int mt = 0; mt < 4; mt++)
        #pragma unroll
        for (int nt = 0; nt < 4; nt++)
            #pragma unroll
            for (int r = 0; r < 4; r++) {
                int row = m0 + wrow + mt*16 + quad*4 + r;
                int col = n0 + wcol + nt*16 + l15;
                if (swz) col = (col & ~31) | (((col & 12) << 1) | ((col & 16) >> 2) | (col & 3));
                C[(size_t)row * N + col] = (bf16)(acc[mt][nt][r] * alpha);
            }
}

// ---------------- flash v3: register P + double-buffered LDS K and V ----------------
__launch_bounds__(256, 2)
__global__ void flash3_kernel(const bf16* __restrict__ q1, const bf16* __restrict__ q2,
                              const bf16* __restrict__ kbase, const bf16* __restrict__ vbase,
                              float* __restrict__ acc_out) {
    __shared__ __align__(16) bf16 Kt[2][64 * 72];   // [buf][kv][feat]
    __shared__ __align__(16) bf16 Vt[2][128 * 72];  // [buf][c][kv] (kv-swizzled order)
    int qb = blockIdx.x, h = blockIdx.y, s = blockIdx.z;
    const bf16* Q  = s ? q2 : q1;
    const bf16* Kp = kbase + (size_t)s * KQ * DFEAT + h * 64;
    const bf16* Vp = vbase + (size_t)s * KQ;          // row pitch 2*KQ
    int t = threadIdx.x, lane = t & 63, wid = t >> 6;
    int quad = lane >> 4, l15 = lane & 15;
    int qbase = qb * 128 + wid * 32;

    // Q B-frags in registers for whole kernel
    bf16x8 qf[2][2];
    #pragma unroll
    for (int mt = 0; mt < 2; mt++)
        #pragma unroll
        for (int ch = 0; ch < 2; ch++)
            qf[mt][ch] = *(const bf16x8*)(Q + (size_t)(qbase + mt*16 + l15) * DFEAT + h*64 + ch*32 + quad*8);

    // staging index maps
    int kr = t >> 2, ks = t & 3;        // K: 4 thr/row, 32B each
    int vr = t >> 1, vs = t & 1;        // V: 2 thr/row, 64B each
    const bf16* kg = Kp + (size_t)kr * DFEAT + ks * 16;
    const bf16* vg = Vp + (size_t)vr * (2 * KQ) + vs * 32;
    bf16* kw0 = &Kt[0][kr * 72 + ks * 16];
    bf16* vw0 = &Vt[0][vr * 72 + vs * 32];
    const int KWB = 64 * 72, VWB = 128 * 72; // buf strides (bf16 elems)

    // prologue: stage iter 0
    {
        uint4 k0 = *(const uint4*)kg, k1 = *(const uint4*)(kg + 8);
        uint4 v0 = *(const uint4*)vg, v1 = *(const uint4*)(vg + 8);
        uint4 v2 = *(const uint4*)(vg + 16), v3 = *(const uint4*)(vg + 24);
        *(uint4*)kw0 = k0; *(uint4*)(kw0 + 8) = k1;
        *(uint4*)vw0 = v0; *(uint4*)(vw0 + 8) = v1;
        *(uint4*)(vw0 + 16) = v2; *(uint4*)(vw0 + 24) = v3;
    }
    __syncthreads();

    f32x4 O[2][8] = {};
    float lrun[2] = {0.f, 0.f};

    for (int it = 0; it < KQ / 64; it++) {
        int p = it & 1;
        int kv0 = it * 64;
        // issue next-iter global loads (consumed at the write below, ~full iter in flight)
        uint4 kn0, kn1, vn0, vn1, vn2, vn3;
        bool more = (it + 1 < KQ / 64);
        if (more) {
            const bf16* kg2 = kg + (size_t)(kv0 + 64) * DFEAT;
            const bf16* vg2 = vg + (kv0 + 64);
            kn0 = *(const uint4*)kg2; kn1 = *(const uint4*)(kg2 + 8);
            vn0 = *(const uint4*)vg2; vn1 = *(const uint4*)(vg2 + 8);
            vn2 = *(const uint4*)(vg2 + 16); vn3 = *(const uint4*)(vg2 + 24);
        }
        const bf16* Kb = &Kt[0][p * KWB];
        const bf16* Vb = &Vt[0][p * VWB];

        // K fragments
        bf16x8 kf[4][2];
        #pragma unroll
        for (int nt = 0; nt < 4; nt++) {
            kf[nt][0] = *(const bf16x8*)&Kb[(nt*16 + l15) * 72 + quad * 8];
            kf[nt][1] = *(const bf16x8*)&Kb[(nt*16 + l15) * 72 + 32 + quad * 8];
        }
        // V fragments
        bf16x8 vbr[8][2];
        #pragma unroll
        for (int ct = 0; ct < 8; ct++) {
            vbr[ct][0] = *(const bf16x8*)&Vb[(ct*16 + l15) * 72 + quad * 8];
            vbr[ct][1] = *(const bf16x8*)&Vb[(ct*16 + l15) * 72 + 32 + quad * 8];
        }

        // S^T = K · Q^T : D[m=kv][n=q]
        f32x4 S[2][4];
        #pragma unroll
        for (int nt = 0; nt < 4; nt++) {
            #pragma unroll
            for (int mt = 0; mt < 2; mt++) {
                f32x4 a = {};
                a = MFMA16(kf[nt][0], qf[mt][0], a);
                a = MFMA16(kf[nt][1], qf[mt][1], a);
                S[mt][nt] = a;
            }
        }
        // exp2 + pack into PV A-frags (identity lane mapping)
        bf16x8 P[2][2];
        #pragma unroll
        for (int mt = 0; mt < 2; mt++) {
            float lsum = 0.f;
            #pragma unroll
            for (int g = 0; g < 2; g++) {
                bf16x8 pp;
                #pragma unroll
                for (int r = 0; r < 4; r++) {
                    float e0 = exp2f(S[mt][2*g][r]);
                    float e1 = exp2f(S[mt][2*g+1][r]);
                    pp[r]     = (bf16)e0;
                    pp[4 + r] = (bf16)e1;
                    lsum += e0 + e1;
                }
                P[mt][g] = pp;
            }
            lrun[mt] += lsum;
        }
        // O += P · VW
        #pragma unroll
        for (int ct = 0; ct < 8; ct++)
            #pragma unroll
            for (int mt = 0; mt < 2; mt++) {
                O[mt][ct] = MFMA16(P[mt][0], vbr[ct][0], O[mt][ct]);
                O[mt][ct] = MFMA16(P[mt][1], vbr[ct][1], O[mt][ct]);
            }
        // write staged regs into the other buffer
        if (more) {
            bf16* kw = kw0 + (p ^ 1) * KWB;
            bf16* vw = vw0 + (p ^ 1) * VWB;
            *(uint4*)kw = kn0; *(uint4*)(kw + 8) = kn1;
            *(uint4*)vw = vn0; *(uint4*)(vw + 8) = vn1;
            *(uint4*)(vw + 16) = vn2; *(uint4*)(vw + 24) = vn3;
        }
        __syncthreads();
    }

    // l reduction across quads (lanes sharing l15)
    #pragma unroll
    for (int mt = 0; mt < 2; mt++) {
        lrun[mt] += __shfl_xor(lrun[mt], 16);
        lrun[mt] += __shfl_xor(lrun[mt], 32);
    }
    #pragma unroll
    for (int mt = 0; mt < 2; mt++)
        #pragma unroll
        for (int r = 0; r < 4; r++) {
            float lr = __shfl(lrun[mt], quad * 4 + r);
            float inv = 1.0f / (8.0f * lr);
            int row = qbase + mt*16 + quad*4 + r;
            #pragma unroll
            for (int ct = 0; ct < 8; ct++)
                atomicAdd(&acc_out[((size_t)s * N_Q + row) * NLAB + ct*16 + l15], O[mt][ct][r] * inv);
        }
}

// ---------------- bias + cast ----------------
__global__ void bias_kernel(const float* __restrict__ acc, const void* __restrict__ bo,
                            void* __restrict__ out, const int* __restrict__ modep) {
    int f32m = *modep;
    int idx = blockIdx.x * 256 + threadIdx.x;
    float v = acc[idx] + loads(bo, idx & (NLAB - 1), f32m);
    if (f32m) ((float*)out)[idx] = v;
    else      ((bf16*)out)[idx] = (bf16)v;
}

extern "C" void kernel_launch(void* const* d_in, const int* in_sizes, int n_in,
                              void* d_out, int out_size, void* d_ws, size_t ws_size,
                              hipStream_t stream) {
    const void* anchor   = d_in[0];
    const void* positive = d_in[1];
    const void* lbfeat   = d_in[2];
    const void* lboh     = d_in[3];
    const void* ulb1     = d_in[5];
    const void* ulb2     = d_in[6];
    const void* fq1i     = d_in[7];
    const void* fq2i     = d_in[8];
    const void* lq1i     = d_in[9];
    const void* lq2i     = d_in[10];
    const void* Wq       = d_in[11];
    const void* Wk       = d_in[12];
    const void* Wo       = d_in[13];
    const void* bo       = d_in[14];

    char* ws = (char*)d_ws;
    int*  counts = (int*)(ws + OFF_COUNTS);
    int*  modep  = (int*)(ws + OFF_MODE);
    int*  flags  = (int*)(ws + OFF_FLAGS);
    int*  sel    = (int*)(ws + OFF_SEL);
    bf16* fq1  = (bf16*)(ws + OFF_FQ1);
    bf16* fq2  = (bf16*)(ws + OFF_FQ2);
    bf16* lq1  = (bf16*)(ws + OFF_LQ1);
    bf16* lq2  = (bf16*)(ws + OFF_LQ2);
    bf16* q1   = (bf16*)(ws + OFF_Q1);
    bf16* q2   = (bf16*)(ws + OFF_Q2);
    bf16* k1   = (bf16*)(ws + OFF_K1);
    bf16* wqT  = (bf16*)(ws + OFF_WQT);
    bf16* wkT  = (bf16*)(ws + OFF_WKT);
    bf16* woT  = (bf16*)(ws + OFF_WOT);
    bf16* vwt  = (bf16*)(ws + OFF_VWT);
    float* accb = (float*)(ws + OFF_ACC);

    hipMemsetAsync(accb, 0, (size_t)2 * N_Q * NLAB * sizeof(float), stream);

    detect_kernel<<<1, 256, 0, stream>>>(anchor, modep);
    flag_kernel<<<dim3(N_Q, 2), 64, 0, stream>>>(ulb1, ulb2, flags, modep);
    scan_kernel<<<2, 1024, 0, stream>>>(flags, sel, counts);
    buildq_kernel<<<dim3(KQ, 2), 128, 0, stream>>>(anchor, positive, lbfeat, lboh, ulb1, ulb2,
                                                   fq1i, fq2i, lq1i, lq2i, sel, counts,
                                                   fq1, fq2, lq1, lq2, modep);
    transpose_kernel<<<dim3(16, 16), 256, 0, stream>>>(Wq, wqT, 512, modep);
    transpose_kernel<<<dim3(16, 16), 256, 0, stream>>>(Wk, wkT, 512, modep);
    transpose_kernel<<<dim3(4, 4), 256, 0, stream>>>(Wo, woT, 128, modep);

    // q = (x @ Wq) * dh^-0.5 * log2(e)  — both streams in one launch (z)
    const float qalpha = 0.125f * 1.44269504088896f;
    gemm_nt<<<dim3(32, 4, 2), 256, 0, stream>>>(anchor, positive, wqT, q1, q2,
                                                4096, 512, 512, qalpha, modep, 1, 0);
    // k = [fq1;fq2] @ Wk  (merged, M=16384)
    gemm_nt<<<dim3(128, 4, 1), 256, 0, stream>>>(fq1, nullptr, wkT, k1, nullptr,
                                                 16384, 512, 512, 1.0f, modep, 0, 0);
    // VW^T = Wo^T @ lq^T, merged N=16384, kv-swizzled columns
    gemm_nt<<<dim3(1, 128, 1), 256, 0, stream>>>(woT, nullptr, lq1, vwt, nullptr,
                                                 128, 16384, 128, 1.0f, modep, 0, 1);

    flash3_kernel<<<dim3(32, NHEAD, 2), 256, 0, stream>>>(q1, q2, k1, vwt, accb);
    bias_kernel<<<(2 * N_Q * NLAB) / 256, 256, 0, stream>>>(accb, bo, d_out, modep);
}